// Round 1
// baseline (12233.946 us; speedup 1.0000x reference)
//
#include <hip/hip_runtime.h>

#define NS  2048
#define RR  116
#define FF  3
#define LLY 4
#define HD  128
#define DN  348
#define DE  13456
#define XZC 2560
#define C1O 1024
#define EPSF 1e-5f

// ---------------------------------------------------------------------------
// Generic tiled GEMM: C[m][n] = sum_k a(m,k)*b(n,k)  (+bias)(+relu)
// TA/TB: 0 => operand stored [m][k] (k-contiguous rows); 1 => stored [k][m]
// BIAS: 0 none, 1 per-row (m), 2 per-col (n)
// ---------------------------------------------------------------------------
template<int TA, int TB, bool BA, bool BB, int BIAS, bool RELU>
__global__ __launch_bounds__(256) void gemm64(
    const float* __restrict__ A, int lda, long long sA,
    const float* __restrict__ B, int ldb, long long sB,
    const float* __restrict__ bias,
    float* __restrict__ C, int ldc, long long sC, int cof,
    int M, int N, int K)
{
  const int s = blockIdx.z;
  const float* Ap = BA ? A + (long long)s * sA : A;
  const float* Bq = BB ? B + (long long)s * sB : B;
  float* Cp = C + (long long)s * sC;
  const int m0 = blockIdx.y * 64, n0 = blockIdx.x * 64;
  __shared__ float As[16][68];
  __shared__ float Bs[16][68];
  const int t = threadIdx.x;
  const int tx = t & 15, ty = t >> 4;
  float acc[4][4] = {};
  for (int kb = 0; kb < K; kb += 16) {
    if (TA == 0) {
      int mm = t >> 2, kk = (t & 3) << 2;
      int gm = m0 + mm, gk = kb + kk;
      float4 v = make_float4(0.f, 0.f, 0.f, 0.f);
      if (gm < M && gk < K) v = *(const float4*)(Ap + (size_t)gm * lda + gk);
      As[kk + 0][mm] = v.x; As[kk + 1][mm] = v.y; As[kk + 2][mm] = v.z; As[kk + 3][mm] = v.w;
    } else {
      int kk = t >> 4, mm = (t & 15) << 2;
      int gm = m0 + mm, gk = kb + kk;
      float4 v = make_float4(0.f, 0.f, 0.f, 0.f);
      if (gk < K && gm < M) v = *(const float4*)(Ap + (size_t)gk * lda + gm);
      *(float4*)&As[kk][mm] = v;
    }
    if (TB == 0) {
      int nn = t >> 2, kk = (t & 3) << 2;
      int gn = n0 + nn, gk = kb + kk;
      float4 v = make_float4(0.f, 0.f, 0.f, 0.f);
      if (gn < N && gk < K) v = *(const float4*)(Bq + (size_t)gn * ldb + gk);
      Bs[kk + 0][nn] = v.x; Bs[kk + 1][nn] = v.y; Bs[kk + 2][nn] = v.z; Bs[kk + 3][nn] = v.w;
    } else {
      int kk = t >> 4, nn = (t & 15) << 2;
      int gn = n0 + nn, gk = kb + kk;
      float4 v = make_float4(0.f, 0.f, 0.f, 0.f);
      if (gk < K && gn < N) v = *(const float4*)(Bq + (size_t)gk * ldb + gn);
      *(float4*)&Bs[kk][nn] = v;
    }
    __syncthreads();
#pragma unroll
    for (int kk = 0; kk < 16; kk++) {
      float4 av = *(const float4*)&As[kk][ty << 2];
      float4 bv = *(const float4*)&Bs[kk][tx << 2];
      acc[0][0] += av.x * bv.x; acc[0][1] += av.x * bv.y; acc[0][2] += av.x * bv.z; acc[0][3] += av.x * bv.w;
      acc[1][0] += av.y * bv.x; acc[1][1] += av.y * bv.y; acc[1][2] += av.y * bv.z; acc[1][3] += av.y * bv.w;
      acc[2][0] += av.z * bv.x; acc[2][1] += av.z * bv.y; acc[2][2] += av.z * bv.z; acc[2][3] += av.z * bv.w;
      acc[3][0] += av.w * bv.x; acc[3][1] += av.w * bv.y; acc[3][2] += av.w * bv.z; acc[3][3] += av.w * bv.w;
    }
    __syncthreads();
  }
#pragma unroll
  for (int i = 0; i < 4; i++) {
    int m = m0 + (ty << 2) + i;
#pragma unroll
    for (int j = 0; j < 4; j++) {
      int n = n0 + (tx << 2) + j;
      if (m < M && n < N) {
        float v = acc[i][j];
        if (BIAS == 1) v += bias[m];
        if (BIAS == 2) v += bias[n];
        if (RELU) v = fmaxf(v, 0.f);
        Cp[(size_t)m * ldc + cof + n] = v;
      }
    }
  }
}

// ---------------------------------------------------------------------------
// Fused per-sample: K = conv1(X), S = K^T K, att = softmax(S), P = att @ V
// (A[m,l] of the reference == P[l,m]; we never materialize att or A)
// ---------------------------------------------------------------------------
__global__ __launch_bounds__(256) void attP(
    const float* __restrict__ Xb, const float* __restrict__ kw,
    const float* __restrict__ kbias, const float* __restrict__ V,
    float* __restrict__ P)
{
  const int s = blockIdx.x;
  __shared__ float Vs[RR * RR];
  __shared__ float Ks[3][RR];
  const float* Vp = V + (size_t)s * DE;
  for (int f = threadIdx.x; f < DE; f += 256) Vs[f] = Vp[f];
  if (threadIdx.x < RR) {
    int l = threadIdx.x;
    float x0 = Xb[(size_t)s * DN + l * 3 + 0];
    float x1 = Xb[(size_t)s * DN + l * 3 + 1];
    float x2 = Xb[(size_t)s * DN + l * 3 + 2];
#pragma unroll
    for (int c = 0; c < 3; c++)
      Ks[c][l] = kw[c * 3 + 0] * x0 + kw[c * 3 + 1] * x1 + kw[c * 3 + 2] * x2 + kbias[c];
  }
  __syncthreads();
  const int wv = threadIdx.x >> 6, ln = threadIdx.x & 63;
  float* Pp = P + (size_t)s * DE;
  const int m2 = ln + 64;
  const bool v2 = (m2 < RR);
  const int m2i = v2 ? m2 : 0;
  for (int l = wv; l < RR; l += 4) {
    float k0 = Ks[0][l], k1 = Ks[1][l], k2 = Ks[2][l];
    float s1 = k0 * Ks[0][ln] + k1 * Ks[1][ln] + k2 * Ks[2][ln];
    float s2 = v2 ? (k0 * Ks[0][m2i] + k1 * Ks[1][m2i] + k2 * Ks[2][m2i]) : -1e30f;
    float mx = fmaxf(s1, s2);
    for (int o = 32; o; o >>= 1) mx = fmaxf(mx, __shfl_xor(mx, o));
    float e1 = __expf(s1 - mx);
    float e2 = v2 ? __expf(s2 - mx) : 0.f;
    float sm = e1 + e2;
    for (int o = 32; o; o >>= 1) sm += __shfl_xor(sm, o);
    float inv = 1.f / sm;
    float a1 = e1 * inv, a2 = e2 * inv;
    float acc1 = 0.f, acc2 = 0.f;
    for (int k = 0; k < RR; k++) {
      float ak = (k < 64) ? __shfl(a1, k) : __shfl(a2, k - 64);
      acc1 += ak * Vs[k * RR + ln];
      acc2 += ak * Vs[k * RR + m2i];
    }
    Pp[l * RR + ln] = acc1;
    if (v2) Pp[l * RR + m2] = acc2;
  }
}

// X1 = (P^T @ X) @ node_w   -> [n, 116, 3]
__global__ void pTx_node(const float* __restrict__ P, const float* __restrict__ Xb,
                         const float* __restrict__ nw, float* __restrict__ X1)
{
  const int s = blockIdx.x;
  const int m = threadIdx.x;
  if (m >= RR) return;
  const float* Pp = P + (size_t)s * DE;
  const float* Xp = Xb + (size_t)s * DN;
  float t0 = 0.f, t1 = 0.f, t2 = 0.f;
  for (int l = 0; l < RR; l++) {
    float p = Pp[l * RR + m];
    t0 += p * Xp[l * 3 + 0];
    t1 += p * Xp[l * 3 + 1];
    t2 += p * Xp[l * 3 + 2];
  }
  float* Op = X1 + (size_t)s * DN + m * 3;
  Op[0] = t0 * nw[0] + t1 * nw[3] + t2 * nw[6];
  Op[1] = t0 * nw[1] + t1 * nw[4] + t2 * nw[7];
  Op[2] = t0 * nw[2] + t1 * nw[5] + t2 * nw[8];
}

// ---------------------------------------------------------------------------
// BatchNorm helpers
// ---------------------------------------------------------------------------
__global__ __launch_bounds__(256) void colstats(
    const float* __restrict__ Y, int ldy, int cof, int ncols, int chunk,
    float* __restrict__ sum, float* __restrict__ sq)
{
  const int cl = threadIdx.x & 63;
  const int c = blockIdx.x * 64 + cl;
  const int r4 = threadIdx.x >> 6;
  const int s0 = blockIdx.y * chunk;
  float a = 0.f, q = 0.f;
  if (c < ncols) {
    for (int r = s0 + r4; r < s0 + chunk; r += 4) {
      float v = Y[(size_t)r * ldy + cof + c];
      a += v; q += v * v;
    }
  }
  __shared__ float la[4][64], lq[4][64];
  la[r4][cl] = a; lq[r4][cl] = q;
  __syncthreads();
  if (threadIdx.x < 64) {
    int cc = blockIdx.x * 64 + threadIdx.x;
    if (cc < ncols) {
      float aa = la[0][threadIdx.x] + la[1][threadIdx.x] + la[2][threadIdx.x] + la[3][threadIdx.x];
      float qq = lq[0][threadIdx.x] + lq[1][threadIdx.x] + lq[2][threadIdx.x] + lq[3][threadIdx.x];
      atomicAdd(&sum[cc], aa);
      atomicAdd(&sq[cc], qq);
    }
  }
}

template<int NC>
__global__ void colnorm(float* __restrict__ Y, int ldy, int cof, float rinv,
                        const float* __restrict__ sum, const float* __restrict__ sq,
                        const float* __restrict__ g, const float* __restrict__ b,
                        unsigned total)
{
  unsigned idx = blockIdx.x * 256u + threadIdx.x;
  if (idx >= total) return;
  unsigned r = idx / NC, c = idx - r * NC;
  float m = sum[c] * rinv;
  float v = sq[c] * rinv - m * m;
  float iv = rsqrtf(v + EPSF);
  size_t o = (size_t)r * ldy + cof + c;
  Y[o] = (Y[o] - m) * iv * g[c] + b[c];
}

template<int LC>
__global__ __launch_bounds__(256) void ncl_stats(
    const float* __restrict__ Xv, float* __restrict__ sum, float* __restrict__ sq)
{
  const int c = blockIdx.x;
  const int s0 = blockIdx.y * 128;
  const int tot = 128 * LC;
  float a = 0.f, q = 0.f;
  for (int f = threadIdx.x; f < tot; f += 256) {
    int sl = f / LC, l = f - sl * LC;
    float v = Xv[((size_t)(s0 + sl) * RR + c) * LC + l];
    a += v; q += v * v;
  }
  for (int o = 32; o; o >>= 1) { a += __shfl_down(a, o); q += __shfl_down(q, o); }
  __shared__ float pa[4], pq[4];
  const int wv = threadIdx.x >> 6;
  if ((threadIdx.x & 63) == 0) { pa[wv] = a; pq[wv] = q; }
  __syncthreads();
  if (threadIdx.x == 0) {
    atomicAdd(&sum[c], pa[0] + pa[1] + pa[2] + pa[3]);
    atomicAdd(&sq[c], pq[0] + pq[1] + pq[2] + pq[3]);
  }
}

template<int LC>
__global__ void ncl_update(float* __restrict__ dst, const float* __restrict__ src,
                           const float* __restrict__ g, const float* __restrict__ b,
                           const float* __restrict__ sum, const float* __restrict__ sq,
                           float invcnt, unsigned total)
{
  unsigned idx = blockIdx.x * 256u + threadIdx.x;
  if (idx >= total) return;
  int c = (int)((idx / LC) % RR);
  float m = sum[c] * invcnt;
  float v = sq[c] * invcnt - m * m;
  float iv = rsqrtf(v + EPSF);
  float z = (src[idx] - m) * iv * g[c] + b[c];
  dst[idx] += fmaxf(z, 0.f);
}

// final tiny classifier: out[s][0..1] = h[s] @ c2_w^T + c2_b
__global__ __launch_bounds__(256) void c2k(const float* __restrict__ Hh,
                                           const float* __restrict__ w,
                                           const float* __restrict__ b,
                                           float* __restrict__ out)
{
  const int s = blockIdx.x;
  float a0 = 0.f, a1 = 0.f;
  for (int j = threadIdx.x; j < C1O; j += 256) {
    float h = Hh[(size_t)s * C1O + j];
    a0 += h * w[j];
    a1 += h * w[C1O + j];
  }
  for (int o = 32; o; o >>= 1) { a0 += __shfl_down(a0, o); a1 += __shfl_down(a1, o); }
  __shared__ float p0[4], p1[4];
  const int wv = threadIdx.x >> 6;
  if ((threadIdx.x & 63) == 0) { p0[wv] = a0; p1[wv] = a1; }
  __syncthreads();
  if (threadIdx.x == 0) {
    out[s * 2 + 0] = p0[0] + p0[1] + p0[2] + p0[3] + b[0];
    out[s * 2 + 1] = p1[0] + p1[1] + p1[2] + p1[3] + b[1];
  }
}

// ---------------------------------------------------------------------------
extern "C" void kernel_launch(void* const* d_in, const int* in_sizes, int n_in,
                              void* d_out, int out_size, void* d_ws, size_t ws_size,
                              hipStream_t stream)
{
  const float* X    = (const float*)d_in[0];
  const float* Z    = (const float*)d_in[1];
  const float* cv1w = (const float*)d_in[2];
  const float* cv1b = (const float*)d_in[3];
  const float* cv2w = (const float*)d_in[4];
  const float* cv2b = (const float*)d_in[5];
  const float* nw   = (const float*)d_in[6];
  const float* ew   = (const float*)d_in[7];
  const float* bng  = (const float*)d_in[8];
  const float* bnb  = (const float*)d_in[9];
  const float* beg  = (const float*)d_in[10];
  const float* beb  = (const float*)d_in[11];
  const float* lnw  = (const float*)d_in[12];
  const float* lnb  = (const float*)d_in[13];
  const float* lng  = (const float*)d_in[14];
  const float* lnbt = (const float*)d_in[15];
  const float* lew  = (const float*)d_in[16];
  const float* leb  = (const float*)d_in[17];
  const float* leg  = (const float*)d_in[18];
  const float* lebt = (const float*)d_in[19];
  const float* fc1w = (const float*)d_in[20];
  const float* fc1b = (const float*)d_in[21];
  const float* fc2w = (const float*)d_in[22];
  const float* fc2b = (const float*)d_in[23];
  float* out = (float*)d_out;

  float* ws = (float*)d_ws;
  float* Zb = ws;                                // [NS, DE]   current Z
  float* BV = Zb + (size_t)NS * DE;              // V, then T1
  float* BP = BV + (size_t)NS * DE;              // P, then Z2
  float* Xb = BP + (size_t)NS * DE;              // [NS, DN]   current X
  float* X1 = Xb + (size_t)NS * DN;              // [NS, DN]
  float* XZ = X1 + (size_t)NS * DN;              // [NS, 2560]
  float* HH = XZ + (size_t)NS * XZC;             // [NS, 1024]
  float* ST = HH + (size_t)NS * C1O;             // stats: 1280 floats

  hipMemcpyAsync(Zb, Z, sizeof(float) * (size_t)NS * DE, hipMemcpyDeviceToDevice, stream);
  hipMemcpyAsync(Xb, X, sizeof(float) * (size_t)NS * DN, hipMemcpyDeviceToDevice, stream);

  const float rinv = 1.f / (float)NS;

  // mlp_head: y = relu(x@w^T + b) into XZ slice; then train-mode BN over rows.
  auto head384 = [&](const float* src, int K, const float* w, const float* bb,
                     const float* g, const float* bt, int cof) {
    gemm64<0, 0, false, false, 2, true><<<dim3(6, NS / 64, 1), 256, 0, stream>>>(
        src, K, 0, w, K, 0, bb, XZ, XZC, 0, cof, NS, 384, K);
    hipMemsetAsync(ST, 0, sizeof(float) * 768, stream);
    colstats<<<dim3(6, 8), 256, 0, stream>>>(XZ, XZC, cof, 384, 256, ST, ST + 384);
    colnorm<384><<<(NS * 384 + 255) / 256, 256, 0, stream>>>(
        XZ, XZC, cof, rinv, ST, ST + 384, g, bt, NS * 384);
  };
  auto head128 = [&](const float* src, int K, const float* w, const float* bb,
                     const float* g, const float* bt, int cof) {
    gemm64<0, 0, false, false, 2, true><<<dim3(2, NS / 64, 1), 256, 0, stream>>>(
        src, K, 0, w, K, 0, bb, XZ, XZC, 0, cof, NS, 128, K);
    hipMemsetAsync(ST, 0, sizeof(float) * 768, stream);
    colstats<<<dim3(2, 8), 256, 0, stream>>>(XZ, XZC, cof, 128, 256, ST, ST + 384);
    colnorm<128><<<(NS * 128 + 255) / 256, 256, 0, stream>>>(
        XZ, XZC, cof, rinv, ST, ST + 384, g, bt, NS * 128);
  };

  head128(Xb, DN, lnw, lnb, lng, lnbt, 0);
  head384(Zb, DE, lew, leb, leg, lebt, 640);

  for (int i = 0; i < LLY; i++) {
    // V = conv2_w[i] @ Z^T + b  (batched; C[o][l])
    gemm64<0, 0, false, true, 1, false><<<dim3(2, 2, NS), 256, 0, stream>>>(
        cv2w + (size_t)i * DE, RR, 0, Zb, RR, (long long)DE,
        cv2b + i * RR, BV, RR, (long long)DE, 0, RR, RR, RR);
    // P = softmax(K^T K) @ V (fused)
    attP<<<NS, 256, 0, stream>>>(Xb, cv1w + i * 9, cv1b + i * 3, BV, BP);
    // X1 = (P^T X) @ node_w[i]   (uses OLD X)
    pTx_node<<<NS, 128, 0, stream>>>(BP, Xb, nw + i * 9, X1);
    // T1 = P^T @ Z  -> BV   (uses OLD Z)
    gemm64<1, 1, true, true, 0, false><<<dim3(2, 2, NS), 256, 0, stream>>>(
        BP, RR, (long long)DE, Zb, RR, (long long)DE,
        nullptr, BV, RR, (long long)DE, 0, RR, RR, RR);
    // Z2 = T1 @ edge_w[i] -> BP
    gemm64<0, 1, true, false, 0, false><<<dim3(2, 2, NS), 256, 0, stream>>>(
        BV, RR, (long long)DE, ew + (size_t)i * DE, RR, 0,
        nullptr, BP, RR, (long long)DE, 0, RR, RR, RR);
    // BN stats (biased var), then Z += relu(bn(Z2)); X += relu(bn(X1))
    hipMemsetAsync(ST + 768, 0, sizeof(float) * 512, stream);
    ncl_stats<RR><<<dim3(RR, 16), 256, 0, stream>>>(BP, ST + 768, ST + 768 + 128);
    ncl_stats<3><<<dim3(RR, 16), 256, 0, stream>>>(X1, ST + 768 + 256, ST + 768 + 384);
    ncl_update<RR><<<((unsigned)NS * DE + 255) / 256, 256, 0, stream>>>(
        Zb, BP, beg + i * RR, beb + i * RR, ST + 768, ST + 768 + 128,
        1.f / (float)(NS * RR), (unsigned)NS * DE);
    ncl_update<3><<<((unsigned)NS * DN + 255) / 256, 256, 0, stream>>>(
        Xb, X1, bng + i * RR, bnb + i * RR, ST + 768 + 256, ST + 768 + 384,
        1.f / (float)(NS * 3), (unsigned)NS * DN);
    // heads on updated Z and X
    head384(Zb, DE, lew + (size_t)(i + 1) * 384 * DE, leb + (i + 1) * 384,
            leg + (i + 1) * 384, lebt + (i + 1) * 384, 640 + (i + 1) * 384);
    head128(Xb, DN, lnw + (size_t)(i + 1) * HD * DN, lnb + (i + 1) * HD,
            lng + (i + 1) * HD, lnbt + (i + 1) * HD, (i + 1) * HD);
  }

  // h = relu(XZ @ c1_w^T + c1_b)
  gemm64<0, 0, false, false, 2, true><<<dim3(C1O / 64, NS / 64, 1), 256, 0, stream>>>(
      XZ, XZC, 0, fc1w, XZC, 0, fc1b, HH, C1O, 0, 0, NS, C1O, XZC);
  // out = h @ c2_w^T + c2_b
  c2k<<<NS, 256, 0, stream>>>(HH, fc2w, fc2b, out);
}

// Round 2
// 6738.029 us; speedup vs baseline: 1.8157x; 1.8157x over previous
//
#include <hip/hip_runtime.h>
#include <hip/hip_bf16.h>

#define NS  2048
#define RR  116
#define FF  3
#define LLY 4
#define HD  128
#define DN  348
#define DE  13456
#define KP  13472   // DE padded to multiple of 32
#define XZC 2560
#define C1O 1024
#define EPSF 1e-5f

typedef __attribute__((ext_vector_type(8))) short short8;
typedef __attribute__((ext_vector_type(4))) float floatx4;

// ---------------------------------------------------------------------------
// Generic tiled fp32 GEMM (kept for small/batched ops)
// C[m][n] = sum_k a(m,k)*b(n,k)  (+bias)(+relu)
// TA/TB: 0 => stored [m][k]; 1 => stored [k][m].  BIAS: 0 none, 1 row, 2 col
// ---------------------------------------------------------------------------
template<int TA, int TB, bool BA, bool BB, int BIAS, bool RELU>
__global__ __launch_bounds__(256) void gemm64(
    const float* __restrict__ A, int lda, long long sA,
    const float* __restrict__ B, int ldb, long long sB,
    const float* __restrict__ bias,
    float* __restrict__ C, int ldc, long long sC, int cof,
    int M, int N, int K)
{
  const int s = blockIdx.z;
  const float* Ap = BA ? A + (long long)s * sA : A;
  const float* Bq = BB ? B + (long long)s * sB : B;
  float* Cp = C + (long long)s * sC;
  const int m0 = blockIdx.y * 64, n0 = blockIdx.x * 64;
  __shared__ float As[16][68];
  __shared__ float Bs[16][68];
  const int t = threadIdx.x;
  const int tx = t & 15, ty = t >> 4;
  float acc[4][4] = {};
  for (int kb = 0; kb < K; kb += 16) {
    if (TA == 0) {
      int mm = t >> 2, kk = (t & 3) << 2;
      int gm = m0 + mm, gk = kb + kk;
      float4 v = make_float4(0.f, 0.f, 0.f, 0.f);
      if (gm < M && gk < K) v = *(const float4*)(Ap + (size_t)gm * lda + gk);
      As[kk + 0][mm] = v.x; As[kk + 1][mm] = v.y; As[kk + 2][mm] = v.z; As[kk + 3][mm] = v.w;
    } else {
      int kk = t >> 4, mm = (t & 15) << 2;
      int gm = m0 + mm, gk = kb + kk;
      float4 v = make_float4(0.f, 0.f, 0.f, 0.f);
      if (gk < K && gm < M) v = *(const float4*)(Ap + (size_t)gk * lda + gm);
      *(float4*)&As[kk][mm] = v;
    }
    if (TB == 0) {
      int nn = t >> 2, kk = (t & 3) << 2;
      int gn = n0 + nn, gk = kb + kk;
      float4 v = make_float4(0.f, 0.f, 0.f, 0.f);
      if (gn < N && gk < K) v = *(const float4*)(Bq + (size_t)gn * ldb + gk);
      Bs[kk + 0][nn] = v.x; Bs[kk + 1][nn] = v.y; Bs[kk + 2][nn] = v.z; Bs[kk + 3][nn] = v.w;
    } else {
      int kk = t >> 4, nn = (t & 15) << 2;
      int gn = n0 + nn, gk = kb + kk;
      float4 v = make_float4(0.f, 0.f, 0.f, 0.f);
      if (gk < K && gn < N) v = *(const float4*)(Bq + (size_t)gk * ldb + gn);
      *(float4*)&Bs[kk][nn] = v;
    }
    __syncthreads();
#pragma unroll
    for (int kk = 0; kk < 16; kk++) {
      float4 av = *(const float4*)&As[kk][ty << 2];
      float4 bv = *(const float4*)&Bs[kk][tx << 2];
      acc[0][0] += av.x * bv.x; acc[0][1] += av.x * bv.y; acc[0][2] += av.x * bv.z; acc[0][3] += av.x * bv.w;
      acc[1][0] += av.y * bv.x; acc[1][1] += av.y * bv.y; acc[1][2] += av.y * bv.z; acc[1][3] += av.y * bv.w;
      acc[2][0] += av.z * bv.x; acc[2][1] += av.z * bv.y; acc[2][2] += av.z * bv.z; acc[2][3] += av.z * bv.w;
      acc[3][0] += av.w * bv.x; acc[3][1] += av.w * bv.y; acc[3][2] += av.w * bv.z; acc[3][3] += av.w * bv.w;
    }
    __syncthreads();
  }
#pragma unroll
  for (int i = 0; i < 4; i++) {
    int m = m0 + (ty << 2) + i;
#pragma unroll
    for (int j = 0; j < 4; j++) {
      int n = n0 + (tx << 2) + j;
      if (m < M && n < N) {
        float v = acc[i][j];
        if (BIAS == 1) v += bias[m];
        if (BIAS == 2) v += bias[n];
        if (RELU) v = fmaxf(v, 0.f);
        Cp[(size_t)m * ldc + cof + n] = v;
      }
    }
  }
}

// ---------------------------------------------------------------------------
// bf16 MFMA TN GEMM: C += A[M][lka] * B[N][lkb]^T  (both k-contiguous bf16)
// 128x128 tile, 4 waves, 16x16x32 MFMA, global_load_lds staging, split-K via
// gridDim.z with fp32 atomicAdd epilogue. Dims must be multiples of 128; lk*
// multiples of 32 (and 8-element aligned).
// ---------------------------------------------------------------------------
__global__ __launch_bounds__(256) void gemm_mfma_tn(
    const ushort* __restrict__ A, int lka,
    const ushort* __restrict__ B, int lkb,
    float* __restrict__ C, int ldc, int cof,
    int ktiles)
{
  __shared__ __align__(16) ushort As[128 * 32];
  __shared__ __align__(16) ushort Bs[128 * 32];
  const int t = threadIdx.x;
  const int m0 = blockIdx.y * 128, n0 = blockIdx.x * 128;
  const int kt0 = (int)((long long)ktiles * blockIdx.z / gridDim.z);
  const int kt1 = (int)((long long)ktiles * (blockIdx.z + 1) / gridDim.z);
  const int w = t >> 6, lane = t & 63;
  const int wm = (w >> 1) << 6, wn = (w & 1) << 6;
  const int fr = lane & 15, quad = lane >> 4;
  const int row0 = t >> 2, row1 = (t + 256) >> 2;
  const int ko = (t & 3) * 8;
  floatx4 acc[4][4] = {};
  for (int kt = kt0; kt < kt1; ++kt) {
    const int kb = kt * 32;
    const ushort* ga0 = A + (size_t)(m0 + row0) * lka + kb + ko;
    const ushort* ga1 = A + (size_t)(m0 + row1) * lka + kb + ko;
    const ushort* gb0 = B + (size_t)(n0 + row0) * lkb + kb + ko;
    const ushort* gb1 = B + (size_t)(n0 + row1) * lkb + kb + ko;
    __builtin_amdgcn_global_load_lds(
        (const __attribute__((address_space(1))) unsigned int*)ga0,
        (__attribute__((address_space(3))) unsigned int*)&As[(size_t)t * 8], 16, 0, 0);
    __builtin_amdgcn_global_load_lds(
        (const __attribute__((address_space(1))) unsigned int*)ga1,
        (__attribute__((address_space(3))) unsigned int*)&As[(size_t)(t + 256) * 8], 16, 0, 0);
    __builtin_amdgcn_global_load_lds(
        (const __attribute__((address_space(1))) unsigned int*)gb0,
        (__attribute__((address_space(3))) unsigned int*)&Bs[(size_t)t * 8], 16, 0, 0);
    __builtin_amdgcn_global_load_lds(
        (const __attribute__((address_space(1))) unsigned int*)gb1,
        (__attribute__((address_space(3))) unsigned int*)&Bs[(size_t)(t + 256) * 8], 16, 0, 0);
    __syncthreads();
    short8 af[4], bf[4];
#pragma unroll
    for (int i = 0; i < 4; i++)
      af[i] = *(const short8*)&As[(wm + i * 16 + fr) * 32 + quad * 8];
#pragma unroll
    for (int j = 0; j < 4; j++)
      bf[j] = *(const short8*)&Bs[(wn + j * 16 + fr) * 32 + quad * 8];
#pragma unroll
    for (int i = 0; i < 4; i++)
#pragma unroll
      for (int j = 0; j < 4; j++)
        acc[i][j] = __builtin_amdgcn_mfma_f32_16x16x32_bf16(af[i], bf[j], acc[i][j], 0, 0, 0);
    __syncthreads();
  }
#pragma unroll
  for (int i = 0; i < 4; i++) {
#pragma unroll
    for (int j = 0; j < 4; j++) {
      int n = n0 + wn + j * 16 + fr;
#pragma unroll
      for (int r = 0; r < 4; r++) {
        int m = m0 + wm + i * 16 + quad * 4 + r;
        atomicAdd(&C[(size_t)m * ldc + cof + n], acc[i][j][r]);
      }
    }
  }
}

// fp32 -> bf16 with K padding (zeros for k >= K)
__global__ void cvt_pad(const float* __restrict__ src, __hip_bfloat16* __restrict__ dst,
                        int K, int Kp, long long total)
{
  long long idx = (long long)blockIdx.x * 256 + threadIdx.x;
  if (idx >= total) return;
  long long r = idx / Kp;
  int k = (int)(idx - r * Kp);
  dst[idx] = (k < K) ? __float2bfloat16(src[r * K + k]) : __float2bfloat16(0.f);
}

// ---------------------------------------------------------------------------
// Fused per-sample: K = conv1(X), S = K^T K, att = softmax(S), P = att @ V
// ---------------------------------------------------------------------------
__global__ __launch_bounds__(256) void attP(
    const float* __restrict__ Xb, const float* __restrict__ kw,
    const float* __restrict__ kbias, const float* __restrict__ V,
    float* __restrict__ P)
{
  const int s = blockIdx.x;
  __shared__ float Vs[RR * RR];
  __shared__ float Ks[3][RR];
  const float* Vp = V + (size_t)s * DE;
  for (int f = threadIdx.x; f < DE; f += 256) Vs[f] = Vp[f];
  if (threadIdx.x < RR) {
    int l = threadIdx.x;
    float x0 = Xb[(size_t)s * DN + l * 3 + 0];
    float x1 = Xb[(size_t)s * DN + l * 3 + 1];
    float x2 = Xb[(size_t)s * DN + l * 3 + 2];
#pragma unroll
    for (int c = 0; c < 3; c++)
      Ks[c][l] = kw[c * 3 + 0] * x0 + kw[c * 3 + 1] * x1 + kw[c * 3 + 2] * x2 + kbias[c];
  }
  __syncthreads();
  const int wv = threadIdx.x >> 6, ln = threadIdx.x & 63;
  float* Pp = P + (size_t)s * DE;
  const int m2 = ln + 64;
  const bool v2 = (m2 < RR);
  const int m2i = v2 ? m2 : 0;
  for (int l = wv; l < RR; l += 4) {
    float k0 = Ks[0][l], k1 = Ks[1][l], k2 = Ks[2][l];
    float s1 = k0 * Ks[0][ln] + k1 * Ks[1][ln] + k2 * Ks[2][ln];
    float s2 = v2 ? (k0 * Ks[0][m2i] + k1 * Ks[1][m2i] + k2 * Ks[2][m2i]) : -1e30f;
    float mx = fmaxf(s1, s2);
    for (int o = 32; o; o >>= 1) mx = fmaxf(mx, __shfl_xor(mx, o));
    float e1 = __expf(s1 - mx);
    float e2 = v2 ? __expf(s2 - mx) : 0.f;
    float sm = e1 + e2;
    for (int o = 32; o; o >>= 1) sm += __shfl_xor(sm, o);
    float inv = 1.f / sm;
    float a1 = e1 * inv, a2 = e2 * inv;
    float acc1 = 0.f, acc2 = 0.f;
    for (int k = 0; k < RR; k++) {
      float ak = (k < 64) ? __shfl(a1, k) : __shfl(a2, k - 64);
      acc1 += ak * Vs[k * RR + ln];
      acc2 += ak * Vs[k * RR + m2i];
    }
    Pp[l * RR + ln] = acc1;
    if (v2) Pp[l * RR + m2] = acc2;
  }
}

// X1 = (P^T @ X) @ node_w   -> [n, 116, 3]
__global__ void pTx_node(const float* __restrict__ P, const float* __restrict__ Xb,
                         const float* __restrict__ nw, float* __restrict__ X1)
{
  const int s = blockIdx.x;
  const int m = threadIdx.x;
  if (m >= RR) return;
  const float* Pp = P + (size_t)s * DE;
  const float* Xp = Xb + (size_t)s * DN;
  float t0 = 0.f, t1 = 0.f, t2 = 0.f;
  for (int l = 0; l < RR; l++) {
    float p = Pp[l * RR + m];
    t0 += p * Xp[l * 3 + 0];
    t1 += p * Xp[l * 3 + 1];
    t2 += p * Xp[l * 3 + 2];
  }
  float* Op = X1 + (size_t)s * DN + m * 3;
  Op[0] = t0 * nw[0] + t1 * nw[3] + t2 * nw[6];
  Op[1] = t0 * nw[1] + t1 * nw[4] + t2 * nw[7];
  Op[2] = t0 * nw[2] + t1 * nw[5] + t2 * nw[8];
}

// ---------------------------------------------------------------------------
// BatchNorm helpers
// ---------------------------------------------------------------------------
__global__ __launch_bounds__(256) void colstats(
    const float* __restrict__ Y, int ldy, int cof, int ncols, int chunk,
    float* __restrict__ sum, float* __restrict__ sq)
{
  const int cl = threadIdx.x & 63;
  const int c = blockIdx.x * 64 + cl;
  const int r4 = threadIdx.x >> 6;
  const int s0 = blockIdx.y * chunk;
  float a = 0.f, q = 0.f;
  if (c < ncols) {
    for (int r = s0 + r4; r < s0 + chunk; r += 4) {
      float v = Y[(size_t)r * ldy + cof + c];
      a += v; q += v * v;
    }
  }
  __shared__ float la[4][64], lq[4][64];
  la[r4][cl] = a; lq[r4][cl] = q;
  __syncthreads();
  if (threadIdx.x < 64) {
    int cc = blockIdx.x * 64 + threadIdx.x;
    if (cc < ncols) {
      float aa = la[0][threadIdx.x] + la[1][threadIdx.x] + la[2][threadIdx.x] + la[3][threadIdx.x];
      float qq = lq[0][threadIdx.x] + lq[1][threadIdx.x] + lq[2][threadIdx.x] + lq[3][threadIdx.x];
      atomicAdd(&sum[cc], aa);
      atomicAdd(&sq[cc], qq);
    }
  }
}

// split-K accumulator epilogue: y = relu(y + bias[c]) in place + col stats
__global__ __launch_bounds__(256) void headpost(
    float* __restrict__ Y, int ldy, int cof, int ncols, int chunk,
    const float* __restrict__ bias,
    float* __restrict__ sum, float* __restrict__ sq)
{
  const int cl = threadIdx.x & 63;
  const int c = blockIdx.x * 64 + cl;
  const int r4 = threadIdx.x >> 6;
  const int s0 = blockIdx.y * chunk;
  float a = 0.f, q = 0.f;
  if (c < ncols) {
    float bb = bias[c];
    for (int r = s0 + r4; r < s0 + chunk; r += 4) {
      size_t o = (size_t)r * ldy + cof + c;
      float v = fmaxf(Y[o] + bb, 0.f);
      Y[o] = v;
      a += v; q += v * v;
    }
  }
  __shared__ float la[4][64], lq[4][64];
  la[r4][cl] = a; lq[r4][cl] = q;
  __syncthreads();
  if (threadIdx.x < 64) {
    int cc = blockIdx.x * 64 + threadIdx.x;
    if (cc < ncols) {
      float aa = la[0][threadIdx.x] + la[1][threadIdx.x] + la[2][threadIdx.x] + la[3][threadIdx.x];
      float qq = lq[0][threadIdx.x] + lq[1][threadIdx.x] + lq[2][threadIdx.x] + lq[3][threadIdx.x];
      atomicAdd(&sum[cc], aa);
      atomicAdd(&sq[cc], qq);
    }
  }
}

// BN normalize, write bf16 (consumed by the bf16 c1 GEMM)
template<int NC>
__global__ void colnormb(const float* __restrict__ Y, __hip_bfloat16* __restrict__ Yb,
                         int ldy, int cof, float rinv,
                         const float* __restrict__ sum, const float* __restrict__ sq,
                         const float* __restrict__ g, const float* __restrict__ b,
                         unsigned total)
{
  unsigned idx = blockIdx.x * 256u + threadIdx.x;
  if (idx >= total) return;
  unsigned r = idx / NC, c = idx - r * NC;
  float m = sum[c] * rinv;
  float v = sq[c] * rinv - m * m;
  float iv = rsqrtf(v + EPSF);
  size_t o = (size_t)r * ldy + cof + c;
  Yb[o] = __float2bfloat16((Y[o] - m) * iv * g[c] + b[c]);
}

template<int LC>
__global__ __launch_bounds__(256) void ncl_stats(
    const float* __restrict__ Xv, float* __restrict__ sum, float* __restrict__ sq)
{
  const int c = blockIdx.x;
  const int s0 = blockIdx.y * 128;
  const int tot = 128 * LC;
  float a = 0.f, q = 0.f;
  for (int f = threadIdx.x; f < tot; f += 256) {
    int sl = f / LC, l = f - sl * LC;
    float v = Xv[((size_t)(s0 + sl) * RR + c) * LC + l];
    a += v; q += v * v;
  }
  for (int o = 32; o; o >>= 1) { a += __shfl_down(a, o); q += __shfl_down(q, o); }
  __shared__ float pa[4], pq[4];
  const int wv = threadIdx.x >> 6;
  if ((threadIdx.x & 63) == 0) { pa[wv] = a; pq[wv] = q; }
  __syncthreads();
  if (threadIdx.x == 0) {
    atomicAdd(&sum[c], pa[0] + pa[1] + pa[2] + pa[3]);
    atomicAdd(&sq[c], pq[0] + pq[1] + pq[2] + pq[3]);
  }
}

template<int LC>
__global__ void ncl_update(float* __restrict__ dst, const float* __restrict__ src,
                           const float* __restrict__ g, const float* __restrict__ b,
                           const float* __restrict__ sum, const float* __restrict__ sq,
                           float invcnt, unsigned total)
{
  unsigned idx = blockIdx.x * 256u + threadIdx.x;
  if (idx >= total) return;
  int c = (int)((idx / LC) % RR);
  float m = sum[c] * invcnt;
  float v = sq[c] * invcnt - m * m;
  float iv = rsqrtf(v + EPSF);
  float z = (src[idx] - m) * iv * g[c] + b[c];
  dst[idx] += fmaxf(z, 0.f);
}

// c1 epilogue: h = relu(h + bias)
__global__ void hpost(float* __restrict__ Hh, const float* __restrict__ b, unsigned total)
{
  unsigned idx = blockIdx.x * 256u + threadIdx.x;
  if (idx >= total) return;
  Hh[idx] = fmaxf(Hh[idx] + b[idx & (C1O - 1)], 0.f);
}

// final tiny classifier
__global__ __launch_bounds__(256) void c2k(const float* __restrict__ Hh,
                                           const float* __restrict__ w,
                                           const float* __restrict__ b,
                                           float* __restrict__ out)
{
  const int s = blockIdx.x;
  float a0 = 0.f, a1 = 0.f;
  for (int j = threadIdx.x; j < C1O; j += 256) {
    float h = Hh[(size_t)s * C1O + j];
    a0 += h * w[j];
    a1 += h * w[C1O + j];
  }
  for (int o = 32; o; o >>= 1) { a0 += __shfl_down(a0, o); a1 += __shfl_down(a1, o); }
  __shared__ float p0[4], p1[4];
  const int wv = threadIdx.x >> 6;
  if ((threadIdx.x & 63) == 0) { p0[wv] = a0; p1[wv] = a1; }
  __syncthreads();
  if (threadIdx.x == 0) {
    out[s * 2 + 0] = p0[0] + p0[1] + p0[2] + p0[3] + b[0];
    out[s * 2 + 1] = p1[0] + p1[1] + p1[2] + p1[3] + b[1];
  }
}

// ---------------------------------------------------------------------------
extern "C" void kernel_launch(void* const* d_in, const int* in_sizes, int n_in,
                              void* d_out, int out_size, void* d_ws, size_t ws_size,
                              hipStream_t stream)
{
  const float* X    = (const float*)d_in[0];
  const float* Z    = (const float*)d_in[1];
  const float* cv1w = (const float*)d_in[2];
  const float* cv1b = (const float*)d_in[3];
  const float* cv2w = (const float*)d_in[4];
  const float* cv2b = (const float*)d_in[5];
  const float* nw   = (const float*)d_in[6];
  const float* ew   = (const float*)d_in[7];
  const float* bng  = (const float*)d_in[8];
  const float* bnb  = (const float*)d_in[9];
  const float* beg  = (const float*)d_in[10];
  const float* beb  = (const float*)d_in[11];
  const float* lnw  = (const float*)d_in[12];
  const float* lnb  = (const float*)d_in[13];
  const float* lng  = (const float*)d_in[14];
  const float* lnbt = (const float*)d_in[15];
  const float* lew  = (const float*)d_in[16];
  const float* leb  = (const float*)d_in[17];
  const float* leg  = (const float*)d_in[18];
  const float* lebt = (const float*)d_in[19];
  const float* fc1w = (const float*)d_in[20];
  const float* fc1b = (const float*)d_in[21];
  const float* fc2w = (const float*)d_in[22];
  const float* fc2b = (const float*)d_in[23];
  float* out = (float*)d_out;

  float* ws = (float*)d_ws;
  float* Zb = ws;                                // [NS, DE] current Z (fp32)
  float* BV = Zb + (size_t)NS * DE;              // V / T1; dead during heads -> Zbh
  float* BP = BV + (size_t)NS * DE;              // P / Z2; dead during heads -> lewh
  float* Xb = BP + (size_t)NS * DE;              // [NS, DN]
  float* X1 = Xb + (size_t)NS * DN;              // [NS, DN]
  float* XZ = X1 + (size_t)NS * DN;              // [NS, 2560] fp32 accumulator
  float* HH = XZ + (size_t)NS * XZC;             // [NS, 1024]
  float* ST = HH + (size_t)NS * C1O;             // stats: 2048 floats
  __hip_bfloat16* XZb  = (__hip_bfloat16*)(ST + 2048);          // [NS,2560] bf16
  __hip_bfloat16* c1wh = XZb + (size_t)NS * XZC;                // [1024,2560] bf16
  // aliased transient bf16 buffers:
  __hip_bfloat16* Zbh  = (__hip_bfloat16*)BV;    // [NS, KP]
  __hip_bfloat16* lwh  = (__hip_bfloat16*)BP;    // [384, KP]

  hipMemcpyAsync(Zb, Z, sizeof(float) * (size_t)NS * DE, hipMemcpyDeviceToDevice, stream);
  hipMemcpyAsync(Xb, X, sizeof(float) * (size_t)NS * DN, hipMemcpyDeviceToDevice, stream);
  hipMemsetAsync(XZ, 0, sizeof(float) * (size_t)NS * XZC, stream);
  hipMemsetAsync(HH, 0, sizeof(float) * (size_t)NS * C1O, stream);
  {
    long long tot = (long long)C1O * XZC;
    cvt_pad<<<(unsigned)((tot + 255) / 256), 256, 0, stream>>>(fc1w, c1wh, XZC, XZC, tot);
  }

  const float rinv = 1.f / (float)NS;

  // edge head: bf16 MFMA split-K GEMM + fused epilogue + BN -> bf16 XZb slice
  auto head384 = [&](const float* w, const float* bb,
                     const float* g, const float* bt, int cof) {
    long long totA = (long long)NS * KP;
    cvt_pad<<<(unsigned)((totA + 255) / 256), 256, 0, stream>>>(Zb, Zbh, DE, KP, totA);
    long long totB = (long long)384 * KP;
    cvt_pad<<<(unsigned)((totB + 255) / 256), 256, 0, stream>>>(w, lwh, DE, KP, totB);
    gemm_mfma_tn<<<dim3(3, 16, 6), 256, 0, stream>>>(
        (const ushort*)Zbh, KP, (const ushort*)lwh, KP, XZ, XZC, cof, KP / 32);
    hipMemsetAsync(ST, 0, sizeof(float) * 768, stream);
    headpost<<<dim3(6, 8), 256, 0, stream>>>(XZ, XZC, cof, 384, 256, bb, ST, ST + 384);
    colnormb<384><<<(NS * 384 + 255) / 256, 256, 0, stream>>>(
        XZ, XZb, XZC, cof, rinv, ST, ST + 384, g, bt, NS * 384);
  };
  // node head: small fp32 GEMM (K=348) + BN -> bf16 XZb slice
  auto head128 = [&](const float* src, const float* w, const float* bb,
                     const float* g, const float* bt, int cof) {
    gemm64<0, 0, false, false, 2, true><<<dim3(2, NS / 64, 1), 256, 0, stream>>>(
        src, DN, 0, w, DN, 0, bb, XZ, XZC, 0, cof, NS, 128, DN);
    hipMemsetAsync(ST, 0, sizeof(float) * 768, stream);
    colstats<<<dim3(2, 8), 256, 0, stream>>>(XZ, XZC, cof, 128, 256, ST, ST + 384);
    colnormb<128><<<(NS * 128 + 255) / 256, 256, 0, stream>>>(
        XZ, XZb, XZC, cof, rinv, ST, ST + 384, g, bt, NS * 128);
  };

  head128(Xb, lnw, lnb, lng, lnbt, 0);
  head384(lew, leb, leg, lebt, 640);

  for (int i = 0; i < LLY; i++) {
    // V = conv2_w[i] @ Z^T + b
    gemm64<0, 0, false, true, 1, false><<<dim3(2, 2, NS), 256, 0, stream>>>(
        cv2w + (size_t)i * DE, RR, 0, Zb, RR, (long long)DE,
        cv2b + i * RR, BV, RR, (long long)DE, 0, RR, RR, RR);
    // P = softmax(K^T K) @ V (fused)
    attP<<<NS, 256, 0, stream>>>(Xb, cv1w + i * 9, cv1b + i * 3, BV, BP);
    // X1 = (P^T X) @ node_w[i]   (uses OLD X)
    pTx_node<<<NS, 128, 0, stream>>>(BP, Xb, nw + i * 9, X1);
    // T1 = P^T @ Z -> BV   (uses OLD Z)
    gemm64<1, 1, true, true, 0, false><<<dim3(2, 2, NS), 256, 0, stream>>>(
        BP, RR, (long long)DE, Zb, RR, (long long)DE,
        nullptr, BV, RR, (long long)DE, 0, RR, RR, RR);
    // Z2 = T1 @ edge_w[i] -> BP
    gemm64<0, 1, true, false, 0, false><<<dim3(2, 2, NS), 256, 0, stream>>>(
        BV, RR, (long long)DE, ew + (size_t)i * DE, RR, 0,
        nullptr, BP, RR, (long long)DE, 0, RR, RR, RR);
    // BN + residual updates
    hipMemsetAsync(ST + 768, 0, sizeof(float) * 512, stream);
    ncl_stats<RR><<<dim3(RR, 16), 256, 0, stream>>>(BP, ST + 768, ST + 768 + 128);
    ncl_stats<3><<<dim3(RR, 16), 256, 0, stream>>>(X1, ST + 768 + 256, ST + 768 + 384);
    ncl_update<RR><<<((unsigned)NS * DE + 255) / 256, 256, 0, stream>>>(
        Zb, BP, beg + i * RR, beb + i * RR, ST + 768, ST + 768 + 128,
        1.f / (float)(NS * RR), (unsigned)NS * DE);
    ncl_update<3><<<((unsigned)NS * DN + 255) / 256, 256, 0, stream>>>(
        Xb, X1, bng + i * RR, bnb + i * RR, ST + 768 + 256, ST + 768 + 384,
        1.f / (float)(NS * 3), (unsigned)NS * DN);
    // heads on updated Z and X  (BV/BP are dead here; reused as bf16 scratch)
    head384(lew + (size_t)(i + 1) * 384 * DE, leb + (i + 1) * 384,
            leg + (i + 1) * 384, lebt + (i + 1) * 384, 640 + (i + 1) * 384);
    head128(Xb, lnw + (size_t)(i + 1) * HD * DN, lnb + (i + 1) * HD,
            lng + (i + 1) * HD, lnbt + (i + 1) * HD, (i + 1) * HD);
  }

  // h = relu(XZ_bf16 @ c1_w^T + c1_b) via bf16 MFMA (split-K=2) + epilogue
  gemm_mfma_tn<<<dim3(C1O / 128, NS / 128, 2), 256, 0, stream>>>(
      (const ushort*)XZb, XZC, (const ushort*)c1wh, XZC, HH, C1O, 0, XZC / 32);
  hpost<<<((unsigned)NS * C1O + 255) / 256, 256, 0, stream>>>(HH, fc1b, (unsigned)NS * C1O);
  // out = h @ c2_w^T + c2_b
  c2k<<<NS, 256, 0, stream>>>(HH, fc2w, fc2b, out);
}

// Round 6
// 3903.321 us; speedup vs baseline: 3.1342x; 1.7262x over previous
//
#include <hip/hip_runtime.h>
#include <hip/hip_bf16.h>

#define NS  2048
#define RR  116
#define LLY 4
#define HD  128
#define DN  348
#define DE  13456
#define KH  16384    // 128x128 per-sample slab
#define SP  136      // padded LDS slab row stride (ushorts)
#define XZC 2560
#define C1O 1024
#define EPSF 1e-5f

typedef __attribute__((ext_vector_type(8))) short short8;
typedef __attribute__((ext_vector_type(4))) float floatx4;

static __device__ __forceinline__ ushort f2bf(float x) {
  union { __hip_bfloat16 b; ushort u; } cv;
  cv.b = __float2bfloat16(x);
  return cv.u;
}
static __device__ __forceinline__ float bf2f(ushort u) {
  union { ushort u; __hip_bfloat16 b; } cv;
  cv.u = u;
  return __bfloat162float(cv.b);
}

#define GLDS16(gsrc, ldst) __builtin_amdgcn_global_load_lds( \
    (const __attribute__((address_space(1))) unsigned int*)(gsrc), \
    (__attribute__((address_space(3))) unsigned int*)(ldst), 16, 0, 0)

// ---------------------------------------------------------------------------
// fp32 tiled GEMM (node heads): C[m][n] = sum_k A[m][k]*B[n][k] + bias[n], relu
// ---------------------------------------------------------------------------
__global__ __launch_bounds__(256) void gemm64(
    const float* __restrict__ A, int lda,
    const float* __restrict__ B, int ldb,
    const float* __restrict__ bias,
    float* __restrict__ C, int ldc, int cof,
    int M, int N, int K)
{
  const int m0 = blockIdx.y * 64, n0 = blockIdx.x * 64;
  __shared__ float As[16][68];
  __shared__ float Bs[16][68];
  const int t = threadIdx.x;
  const int tx = t & 15, ty = t >> 4;
  float acc[4][4] = {};
  for (int kb = 0; kb < K; kb += 16) {
    {
      int mm = t >> 2, kk = (t & 3) << 2;
      int gm = m0 + mm, gk = kb + kk;
      float4 v = make_float4(0.f, 0.f, 0.f, 0.f);
      if (gm < M && gk < K) v = *(const float4*)(A + (size_t)gm * lda + gk);
      As[kk + 0][mm] = v.x; As[kk + 1][mm] = v.y; As[kk + 2][mm] = v.z; As[kk + 3][mm] = v.w;
      int gn = n0 + mm;
      float4 u = make_float4(0.f, 0.f, 0.f, 0.f);
      if (gn < N && gk < K) u = *(const float4*)(B + (size_t)gn * ldb + gk);
      Bs[kk + 0][mm] = u.x; Bs[kk + 1][mm] = u.y; Bs[kk + 2][mm] = u.z; Bs[kk + 3][mm] = u.w;
    }
    __syncthreads();
#pragma unroll
    for (int kk = 0; kk < 16; kk++) {
      float4 av = *(const float4*)&As[kk][ty << 2];
      float4 bv = *(const float4*)&Bs[kk][tx << 2];
      acc[0][0] += av.x * bv.x; acc[0][1] += av.x * bv.y; acc[0][2] += av.x * bv.z; acc[0][3] += av.x * bv.w;
      acc[1][0] += av.y * bv.x; acc[1][1] += av.y * bv.y; acc[1][2] += av.y * bv.z; acc[1][3] += av.y * bv.w;
      acc[2][0] += av.z * bv.x; acc[2][1] += av.z * bv.y; acc[2][2] += av.z * bv.z; acc[2][3] += av.z * bv.w;
      acc[3][0] += av.w * bv.x; acc[3][1] += av.w * bv.y; acc[3][2] += av.w * bv.z; acc[3][3] += av.w * bv.w;
    }
    __syncthreads();
  }
#pragma unroll
  for (int i = 0; i < 4; i++) {
    int m = m0 + (ty << 2) + i;
#pragma unroll
    for (int j = 0; j < 4; j++) {
      int n = n0 + (tx << 2) + j;
      if (m < M && n < N)
        C[(size_t)m * ldc + cof + n] = fmaxf(acc[i][j] + bias[n], 0.f);
    }
  }
}

// ---------------------------------------------------------------------------
// bf16 MFMA TN GEMM (big heads): C += A[M][lka]*B[N][lkb]^T, split-K atomics
// ---------------------------------------------------------------------------
__global__ __launch_bounds__(256) void gemm_mfma_tn(
    const ushort* __restrict__ A, int lka,
    const ushort* __restrict__ B, int lkb,
    float* __restrict__ C, int ldc, int cof,
    int ktiles)
{
  __shared__ __align__(16) ushort As[128 * 32];
  __shared__ __align__(16) ushort Bs[128 * 32];
  const int t = threadIdx.x;
  const int m0 = blockIdx.y * 128, n0 = blockIdx.x * 128;
  const int kt0 = (int)((long long)ktiles * blockIdx.z / gridDim.z);
  const int kt1 = (int)((long long)ktiles * (blockIdx.z + 1) / gridDim.z);
  const int w = t >> 6, lane = t & 63;
  const int wm = (w >> 1) << 6, wn = (w & 1) << 6;
  const int fr = lane & 15, quad = lane >> 4;
  const int row0 = t >> 2, row1 = (t + 256) >> 2;
  const int ko = (t & 3) * 8;
  floatx4 acc[4][4] = {};
  for (int kt = kt0; kt < kt1; ++kt) {
    const int kb = kt * 32;
    GLDS16(A + (size_t)(m0 + row0) * lka + kb + ko, &As[(size_t)t * 8]);
    GLDS16(A + (size_t)(m0 + row1) * lka + kb + ko, &As[(size_t)(t + 256) * 8]);
    GLDS16(B + (size_t)(n0 + row0) * lkb + kb + ko, &Bs[(size_t)t * 8]);
    GLDS16(B + (size_t)(n0 + row1) * lkb + kb + ko, &Bs[(size_t)(t + 256) * 8]);
    __syncthreads();
    short8 af[4], bf[4];
#pragma unroll
    for (int i = 0; i < 4; i++)
      af[i] = *(const short8*)&As[(wm + i * 16 + fr) * 32 + quad * 8];
#pragma unroll
    for (int j = 0; j < 4; j++)
      bf[j] = *(const short8*)&Bs[(wn + j * 16 + fr) * 32 + quad * 8];
#pragma unroll
    for (int i = 0; i < 4; i++)
#pragma unroll
      for (int j = 0; j < 4; j++)
        acc[i][j] = __builtin_amdgcn_mfma_f32_16x16x32_bf16(af[i], bf[j], acc[i][j], 0, 0, 0);
    __syncthreads();
  }
#pragma unroll
  for (int i = 0; i < 4; i++) {
#pragma unroll
    for (int j = 0; j < 4; j++) {
      int n = n0 + wn + j * 16 + fr;
#pragma unroll
      for (int r = 0; r < 4; r++) {
        int m = m0 + wm + i * 16 + quad * 4 + r;
        atomicAdd(&C[(size_t)m * ldc + cof + n], acc[i][j][r]);
      }
    }
  }
}

// ---------------------------------------------------------------------------
// fusedG12: per sample s:
//   G1: Vt[l][o] = sum_i Z[l][i]*w2[o][i] + b2[o]   (split-bf16, acc fp32)
//   G2: A[m][l]  = sum_k Vt[m][k]*att[l][k]         (att generated in-regs)
// Z from global hi/lo slabs; Vt kept in LDS hi/lo; A stored to global hi/lo.
// ---------------------------------------------------------------------------
__global__ __launch_bounds__(256) void fusedG12(
    const ushort* __restrict__ ZHi, const ushort* __restrict__ ZLo,
    const ushort* __restrict__ WHi, const ushort* __restrict__ WLo,
    const float* __restrict__ b2, const float* __restrict__ Kf,
    ushort* __restrict__ AHi, ushort* __restrict__ ALo)
{
  __shared__ __align__(16) ushort VtHi[128 * SP];
  __shared__ __align__(16) ushort VtLo[128 * SP];
  __shared__ __align__(16) ushort tAhi[4096], tAlo[4096], tBhi[4096], tBlo[4096];
  __shared__ float Ks0[128], Ks1[128], Ks2[128], Mrow[128], Minv[128];
  const int s = blockIdx.x;
  const int t = threadIdx.x;
  if (t < 128) {
    const float* kf = Kf + (size_t)s * 384;
    Ks0[t] = kf[t]; Ks1[t] = kf[128 + t]; Ks2[t] = kf[256 + t];
  }
  __syncthreads();
  if (t < 128) {
    if (t < RR) {
      float k0 = Ks0[t], k1 = Ks1[t], k2 = Ks2[t];
      float mx = -3.0e38f;
      for (int k = 0; k < RR; k++)
        mx = fmaxf(mx, k0 * Ks0[k] + k1 * Ks1[k] + k2 * Ks2[k]);
      float sm = 0.f;
      for (int k = 0; k < RR; k++)
        sm += __expf(k0 * Ks0[k] + k1 * Ks1[k] + k2 * Ks2[k] - mx);
      Mrow[t] = mx; Minv[t] = 1.f / sm;
    } else { Mrow[t] = 0.f; Minv[t] = 0.f; }
  }
  const int w = t >> 6, lane = t & 63;
  const int wm = (w >> 1) << 6, wn = (w & 1) << 6;
  const int fr = lane & 15, quad = lane >> 4;
  const int r0 = t >> 2, c8 = (t & 3) * 8;
  // ---- G1 ----
  floatx4 acc[4][4] = {};
  for (int kt = 0; kt < 4; kt++) {
    const int kb = kt * 32;
    const size_t go = (size_t)s * KH + (size_t)r0 * 128 + kb + c8;
    GLDS16(ZHi + go, &tAhi[t * 8]);
    GLDS16(ZHi + go + 64 * 128, &tAhi[2048 + t * 8]);
    GLDS16(ZLo + go, &tAlo[t * 8]);
    GLDS16(ZLo + go + 64 * 128, &tAlo[2048 + t * 8]);
    const size_t wo = (size_t)r0 * 128 + kb + c8;
    GLDS16(WHi + wo, &tBhi[t * 8]);
    GLDS16(WHi + wo + 64 * 128, &tBhi[2048 + t * 8]);
    GLDS16(WLo + wo, &tBlo[t * 8]);
    GLDS16(WLo + wo + 64 * 128, &tBlo[2048 + t * 8]);
    __syncthreads();
    short8 ah[4], al[4], bh[4], bl[4];
#pragma unroll
    for (int i = 0; i < 4; i++) {
      ah[i] = *(const short8*)&tAhi[(wm + i * 16 + fr) * 32 + quad * 8];
      al[i] = *(const short8*)&tAlo[(wm + i * 16 + fr) * 32 + quad * 8];
    }
#pragma unroll
    for (int j = 0; j < 4; j++) {
      bh[j] = *(const short8*)&tBhi[(wn + j * 16 + fr) * 32 + quad * 8];
      bl[j] = *(const short8*)&tBlo[(wn + j * 16 + fr) * 32 + quad * 8];
    }
#pragma unroll
    for (int i = 0; i < 4; i++)
#pragma unroll
      for (int j = 0; j < 4; j++) {
        acc[i][j] = __builtin_amdgcn_mfma_f32_16x16x32_bf16(ah[i], bh[j], acc[i][j], 0, 0, 0);
        acc[i][j] = __builtin_amdgcn_mfma_f32_16x16x32_bf16(al[i], bh[j], acc[i][j], 0, 0, 0);
        acc[i][j] = __builtin_amdgcn_mfma_f32_16x16x32_bf16(ah[i], bl[j], acc[i][j], 0, 0, 0);
      }
    __syncthreads();
  }
  // bias + split into LDS Vt slabs
#pragma unroll
  for (int i = 0; i < 4; i++) {
#pragma unroll
    for (int j = 0; j < 4; j++) {
      int n = wn + j * 16 + fr;
      float bb = (n < RR) ? b2[n] : 0.f;
#pragma unroll
      for (int r = 0; r < 4; r++) {
        int m = wm + i * 16 + quad * 4 + r;
        float v = acc[i][j][r] + bb;
        ushort h = f2bf(v);
        VtHi[m * SP + n] = h;
        VtLo[m * SP + n] = f2bf(v - bf2f(h));
      }
    }
  }
  __syncthreads();
  // ---- G2 ----
  floatx4 ac2[4][4] = {};
  for (int kt = 0; kt < 4; kt++) {
    const int kb = kt * 32;
    short8 ah[4], al[4];
#pragma unroll
    for (int i = 0; i < 4; i++) {
      ah[i] = *(const short8*)&VtHi[(wm + i * 16 + fr) * SP + kb + quad * 8];
      al[i] = *(const short8*)&VtLo[(wm + i * 16 + fr) * SP + kb + quad * 8];
    }
#pragma unroll
    for (int j = 0; j < 4; j++) {
      int l = wn + j * 16 + fr;
      bool lv = (l < RR);
      float k0 = 0.f, k1 = 0.f, k2 = 0.f, ml = 0.f, iv = 0.f;
      if (lv) { k0 = Ks0[l]; k1 = Ks1[l]; k2 = Ks2[l]; ml = Mrow[l]; iv = Minv[l]; }
      short8 bh, bl;
#pragma unroll
      for (int e = 0; e < 8; e++) {
        int k = kb + quad * 8 + e;
        float a = 0.f;
        if (lv && k < RR)
          a = __expf(k0 * Ks0[k] + k1 * Ks1[k] + k2 * Ks2[k] - ml) * iv;
        ushort h = f2bf(a);
        ((ushort*)&bh)[e] = h;
        ((ushort*)&bl)[e] = f2bf(a - bf2f(h));
      }
#pragma unroll
      for (int i = 0; i < 4; i++) {
        ac2[i][j] = __builtin_amdgcn_mfma_f32_16x16x32_bf16(ah[i], bh, ac2[i][j], 0, 0, 0);
        ac2[i][j] = __builtin_amdgcn_mfma_f32_16x16x32_bf16(al[i], bh, ac2[i][j], 0, 0, 0);
        ac2[i][j] = __builtin_amdgcn_mfma_f32_16x16x32_bf16(ah[i], bl, ac2[i][j], 0, 0, 0);
      }
    }
  }
  ushort* CH = AHi + (size_t)s * KH;
  ushort* CL = ALo + (size_t)s * KH;
#pragma unroll
  for (int i = 0; i < 4; i++) {
#pragma unroll
    for (int j = 0; j < 4; j++) {
      int n = wn + j * 16 + fr;
#pragma unroll
      for (int r = 0; r < 4; r++) {
        int m = wm + i * 16 + quad * 4 + r;
        float v = ac2[i][j][r];
        ushort h = f2bf(v);
        CH[m * 128 + n] = h;
        CL[m * 128 + n] = f2bf(v - bf2f(h));
      }
    }
  }
}

// ---------------------------------------------------------------------------
// fusedG34: per sample s:
//   G3: W1[j][l] = sum_k Z[j][k]*ewT[l][k]   -> W1T hi/lo slab in LDS
//   G4: Z2[i][l] = sum_j A[i][j]*W1T[l][j]   -> split store in place over A
// ---------------------------------------------------------------------------
__global__ __launch_bounds__(256) void fusedG34(
    const ushort* __restrict__ ZHi, const ushort* __restrict__ ZLo,
    const ushort* __restrict__ EHi, const ushort* __restrict__ ELo,
    ushort* __restrict__ AHi, ushort* __restrict__ ALo)
{
  __shared__ __align__(16) ushort WtHi[128 * SP];
  __shared__ __align__(16) ushort WtLo[128 * SP];
  __shared__ __align__(16) ushort tAhi[4096], tAlo[4096], tBhi[4096], tBlo[4096];
  const int s = blockIdx.x;
  const int t = threadIdx.x;
  const int w = t >> 6, lane = t & 63;
  const int wm = (w >> 1) << 6, wn = (w & 1) << 6;
  const int fr = lane & 15, quad = lane >> 4;
  const int r0 = t >> 2, c8 = (t & 3) * 8;
  // ---- G3 ----
  floatx4 acc[4][4] = {};
  for (int kt = 0; kt < 4; kt++) {
    const int kb = kt * 32;
    const size_t go = (size_t)s * KH + (size_t)r0 * 128 + kb + c8;
    GLDS16(ZHi + go, &tAhi[t * 8]);
    GLDS16(ZHi + go + 64 * 128, &tAhi[2048 + t * 8]);
    GLDS16(ZLo + go, &tAlo[t * 8]);
    GLDS16(ZLo + go + 64 * 128, &tAlo[2048 + t * 8]);
    const size_t eo = (size_t)r0 * 128 + kb + c8;
    GLDS16(EHi + eo, &tBhi[t * 8]);
    GLDS16(EHi + eo + 64 * 128, &tBhi[2048 + t * 8]);
    GLDS16(ELo + eo, &tBlo[t * 8]);
    GLDS16(ELo + eo + 64 * 128, &tBlo[2048 + t * 8]);
    __syncthreads();
    short8 ah[4], al[4], bh[4], bl[4];
#pragma unroll
    for (int i = 0; i < 4; i++) {
      ah[i] = *(const short8*)&tAhi[(wm + i * 16 + fr) * 32 + quad * 8];
      al[i] = *(const short8*)&tAlo[(wm + i * 16 + fr) * 32 + quad * 8];
    }
#pragma unroll
    for (int j = 0; j < 4; j++) {
      bh[j] = *(const short8*)&tBhi[(wn + j * 16 + fr) * 32 + quad * 8];
      bl[j] = *(const short8*)&tBlo[(wn + j * 16 + fr) * 32 + quad * 8];
    }
#pragma unroll
    for (int i = 0; i < 4; i++)
#pragma unroll
      for (int j = 0; j < 4; j++) {
        acc[i][j] = __builtin_amdgcn_mfma_f32_16x16x32_bf16(ah[i], bh[j], acc[i][j], 0, 0, 0);
        acc[i][j] = __builtin_amdgcn_mfma_f32_16x16x32_bf16(al[i], bh[j], acc[i][j], 0, 0, 0);
        acc[i][j] = __builtin_amdgcn_mfma_f32_16x16x32_bf16(ah[i], bl[j], acc[i][j], 0, 0, 0);
      }
    __syncthreads();
  }
  // transposed split store W1 -> W1T slabs
#pragma unroll
  for (int i = 0; i < 4; i++) {
#pragma unroll
    for (int j = 0; j < 4; j++) {
      int n = wn + j * 16 + fr;
      int mb = wm + i * 16 + quad * 4;
      ushort4 ph, pl;
#pragma unroll
      for (int r = 0; r < 4; r++) {
        float v = acc[i][j][r];
        ushort h = f2bf(v);
        ((ushort*)&ph)[r] = h;
        ((ushort*)&pl)[r] = f2bf(v - bf2f(h));
      }
      *(ushort4*)&WtHi[n * SP + mb] = ph;
      *(ushort4*)&WtLo[n * SP + mb] = pl;
    }
  }
  __syncthreads();
  // ---- G4 ----
  floatx4 ac2[4][4] = {};
  for (int kt = 0; kt < 4; kt++) {
    const int kb = kt * 32;
    const size_t go = (size_t)s * KH + (size_t)r0 * 128 + kb + c8;
    GLDS16(AHi + go, &tAhi[t * 8]);
    GLDS16(AHi + go + 64 * 128, &tAhi[2048 + t * 8]);
    GLDS16(ALo + go, &tAlo[t * 8]);
    GLDS16(ALo + go + 64 * 128, &tAlo[2048 + t * 8]);
    __syncthreads();
    short8 ah[4], al[4], bh[4], bl[4];
#pragma unroll
    for (int i = 0; i < 4; i++) {
      ah[i] = *(const short8*)&tAhi[(wm + i * 16 + fr) * 32 + quad * 8];
      al[i] = *(const short8*)&tAlo[(wm + i * 16 + fr) * 32 + quad * 8];
    }
#pragma unroll
    for (int j = 0; j < 4; j++) {
      bh[j] = *(const short8*)&WtHi[(wn + j * 16 + fr) * SP + kb + quad * 8];
      bl[j] = *(const short8*)&WtLo[(wn + j * 16 + fr) * SP + kb + quad * 8];
    }
#pragma unroll
    for (int i = 0; i < 4; i++)
#pragma unroll
      for (int j = 0; j < 4; j++) {
        ac2[i][j] = __builtin_amdgcn_mfma_f32_16x16x32_bf16(ah[i], bh[j], ac2[i][j], 0, 0, 0);
        ac2[i][j] = __builtin_amdgcn_mfma_f32_16x16x32_bf16(al[i], bh[j], ac2[i][j], 0, 0, 0);
        ac2[i][j] = __builtin_amdgcn_mfma_f32_16x16x32_bf16(ah[i], bl[j], ac2[i][j], 0, 0, 0);
      }
    __syncthreads();
  }
  ushort* CH = AHi + (size_t)s * KH;
  ushort* CL = ALo + (size_t)s * KH;
#pragma unroll
  for (int i = 0; i < 4; i++) {
#pragma unroll
    for (int j = 0; j < 4; j++) {
      int n = wn + j * 16 + fr;
#pragma unroll
      for (int r = 0; r < 4; r++) {
        int m = wm + i * 16 + quad * 4 + r;
        float v = ac2[i][j][r];
        ushort h = f2bf(v);
        CH[m * 128 + n] = h;
        CL[m * 128 + n] = f2bf(v - bf2f(h));
      }
    }
  }
}

// K precompute: Kf[s][c*128+l] = conv1_w[c]·X[s][l] + b[c]  (0 for l>=RR)
__global__ void kprep(const float* __restrict__ Xb, const float* __restrict__ kw,
                      const float* __restrict__ kb, float* __restrict__ Kf)
{
  int idx = blockIdx.x * 256 + threadIdx.x;
  if (idx >= NS * 384) return;
  int s = idx / 384, r = idx - s * 384;
  int c = r >> 7, l = r & 127;
  float v = 0.f;
  if (l < RR) {
    const float* xp = Xb + (size_t)s * DN + l * 3;
    v = kw[c * 3 + 0] * xp[0] + kw[c * 3 + 1] * xp[1] + kw[c * 3 + 2] * xp[2] + kb[c];
  }
  Kf[idx] = v;
}

// initial Z -> hi/lo slabs (zero-padded)
__global__ __launch_bounds__(256) void cvtZ0(
    const float* __restrict__ Z, ushort* __restrict__ ZHi, ushort* __restrict__ ZLo)
{
  const int s = blockIdx.x;
  const float* Zp = Z + (size_t)s * DE;
  ushort* h = ZHi + (size_t)s * KH;
  ushort* lo = ZLo + (size_t)s * KH;
  for (int idx = threadIdx.x; idx < KH; idx += 256) {
    int l = idx >> 7, i = idx & 127;
    if ((l < RR) && (i < RR)) {
      float v = Zp[l * RR + i];
      ushort hh = f2bf(v);
      h[idx] = hh; lo[idx] = f2bf(v - bf2f(hh));
    } else { h[idx] = 0; lo[idx] = 0; }
  }
}

// weight prep: w2 pair [o][i]; ewT pair [l][k]=ew[k][l]  (padded, all layers)
__global__ void wprep2(const float* __restrict__ w2, const float* __restrict__ ew,
                       ushort* __restrict__ w2Hi, ushort* __restrict__ w2Lo,
                       ushort* __restrict__ eHi, ushort* __restrict__ eLo)
{
  int idx = blockIdx.x * 256 + threadIdx.x;   // 4*16384
  int ly = idx >> 14, k = idx & (KH - 1);
  int r = k >> 7, c = k & 127;
  bool v = (r < RR) && (c < RR);
  float a = v ? w2[ly * DE + r * RR + c] : 0.f;
  float b = v ? ew[ly * DE + c * RR + r] : 0.f;
  ushort ha = f2bf(a), hb = f2bf(b);
  w2Hi[idx] = ha; w2Lo[idx] = f2bf(a - bf2f(ha));
  eHi[idx] = hb; eLo[idx] = f2bf(b - bf2f(hb));
}

// lew head weights: [384][13456] fp32 -> [384][16384] bf16 hole-padded
__global__ void lewprep(const float* __restrict__ src, ushort* __restrict__ dst)
{
  int idx = blockIdx.x * 256 + threadIdx.x;   // 384*16384
  int h = idx >> 14, k = idx & (KH - 1);
  int l = k >> 7, i = k & 127;
  bool v = (l < RR) && (i < RR);
  dst[idx] = v ? f2bf(src[(size_t)h * DE + l * RR + i]) : (ushort)0;
}

// fp32 -> bf16 plain convert (c1 weights)
__global__ void cvt_pad(const float* __restrict__ src, ushort* __restrict__ dst,
                        long long total)
{
  long long idx = (long long)blockIdx.x * 256 + threadIdx.x;
  if (idx < total) dst[idx] = f2bf(src[idx]);
}

// X1 = (A @ X) @ node_w   (A from hi/lo pair)
__global__ void pTx_node(const ushort* __restrict__ AHi, const ushort* __restrict__ ALo,
                         const float* __restrict__ Xb,
                         const float* __restrict__ nw, float* __restrict__ X1)
{
  const int s = blockIdx.x;
  const int m = threadIdx.x;
  if (m >= RR) return;
  const ushort* Ah = AHi + (size_t)s * KH + m * 128;
  const ushort* Al = ALo + (size_t)s * KH + m * 128;
  const float* Xp = Xb + (size_t)s * DN;
  float t0 = 0.f, t1 = 0.f, t2 = 0.f;
  for (int l = 0; l < RR; l++) {
    float p = bf2f(Ah[l]) + bf2f(Al[l]);
    t0 += p * Xp[l * 3 + 0];
    t1 += p * Xp[l * 3 + 1];
    t2 += p * Xp[l * 3 + 2];
  }
  float* Op = X1 + (size_t)s * DN + m * 3;
  Op[0] = t0 * nw[0] + t1 * nw[3] + t2 * nw[6];
  Op[1] = t0 * nw[1] + t1 * nw[4] + t2 * nw[7];
  Op[2] = t0 * nw[2] + t1 * nw[5] + t2 * nw[8];
}

// ---------------------------------------------------------------------------
// BN helpers
// ---------------------------------------------------------------------------
__global__ __launch_bounds__(256) void colstats(
    const float* __restrict__ Y, int ldy, int cof, int ncols, int chunk,
    float* __restrict__ sum, float* __restrict__ sq)
{
  const int cl = threadIdx.x & 63;
  const int c = blockIdx.x * 64 + cl;
  const int r4 = threadIdx.x >> 6;
  const int s0 = blockIdx.y * chunk;
  float a = 0.f, q = 0.f;
  if (c < ncols) {
    for (int r = s0 + r4; r < s0 + chunk; r += 4) {
      float v = Y[(size_t)r * ldy + cof + c];
      a += v; q += v * v;
    }
  }
  __shared__ float la[4][64], lq[4][64];
  la[r4][cl] = a; lq[r4][cl] = q;
  __syncthreads();
  if (threadIdx.x < 64) {
    int cc = blockIdx.x * 64 + threadIdx.x;
    if (cc < ncols) {
      float aa = la[0][threadIdx.x] + la[1][threadIdx.x] + la[2][threadIdx.x] + la[3][threadIdx.x];
      float qq = lq[0][threadIdx.x] + lq[1][threadIdx.x] + lq[2][threadIdx.x] + lq[3][threadIdx.x];
      atomicAdd(&sum[cc], aa);
      atomicAdd(&sq[cc], qq);
    }
  }
}

__global__ __launch_bounds__(256) void headpost(
    float* __restrict__ Y, int ldy, int cof, int ncols, int chunk,
    const float* __restrict__ bias,
    float* __restrict__ sum, float* __restrict__ sq)
{
  const int cl = threadIdx.x & 63;
  const int c = blockIdx.x * 64 + cl;
  const int r4 = threadIdx.x >> 6;
  const int s0 = blockIdx.y * chunk;
  float a = 0.f, q = 0.f;
  if (c < ncols) {
    float bb = bias[c];
    for (int r = s0 + r4; r < s0 + chunk; r += 4) {
      size_t o = (size_t)r * ldy + cof + c;
      float v = fmaxf(Y[o] + bb, 0.f);
      Y[o] = v;
      a += v; q += v * v;
    }
  }
  __shared__ float la[4][64], lq[4][64];
  la[r4][cl] = a; lq[r4][cl] = q;
  __syncthreads();
  if (threadIdx.x < 64) {
    int cc = blockIdx.x * 64 + threadIdx.x;
    if (cc < ncols) {
      float aa = la[0][threadIdx.x] + la[1][threadIdx.x] + la[2][threadIdx.x] + la[3][threadIdx.x];
      float qq = lq[0][threadIdx.x] + lq[1][threadIdx.x] + lq[2][threadIdx.x] + lq[3][threadIdx.x];
      atomicAdd(&sum[cc], aa);
      atomicAdd(&sq[cc], qq);
    }
  }
}

template<int NC>
__global__ void colnormb(const float* __restrict__ Y, ushort* __restrict__ Yb,
                         int ldy, int cof, float rinv,
                         const float* __restrict__ sum, const float* __restrict__ sq,
                         const float* __restrict__ g, const float* __restrict__ b,
                         unsigned total)
{
  unsigned idx = blockIdx.x * 256u + threadIdx.x;
  if (idx >= total) return;
  unsigned r = idx / NC, c = idx - r * NC;
  float m = sum[c] * rinv;
  float v = sq[c] * rinv - m * m;
  float iv = rsqrtf(v + EPSF);
  size_t o = (size_t)r * ldy + cof + c;
  Yb[o] = f2bf((Y[o] - m) * iv * g[c] + b[c]);
}

// stats over Z2 hi/lo slabs [s][128(i)][128(l)], channel = i (pad cols are 0)
__global__ __launch_bounds__(256) void ncl_statsb_pair(
    const ushort* __restrict__ ZsHi, const ushort* __restrict__ ZsLo,
    float* __restrict__ sum, float* __restrict__ sq)
{
  const int c = blockIdx.x;
  const int s0 = blockIdx.y * 128;
  float a = 0.f, q = 0.f;
  for (int f = threadIdx.x; f < 2048; f += 256) {
    size_t off = (size_t)(s0 + (f >> 4)) * KH + c * 128 + (f & 15) * 8;
    const ushort* ph = ZsHi + off;
    const ushort* pl = ZsLo + off;
#pragma unroll
    for (int e = 0; e < 8; e++) {
      float v = bf2f(ph[e]) + bf2f(pl[e]);
      a += v; q += v * v;
    }
  }
  for (int o = 32; o; o >>= 1) { a += __shfl_down(a, o); q += __shfl_down(q, o); }
  __shared__ float pa[4], pq[4];
  const int wv = threadIdx.x >> 6;
  if ((threadIdx.x & 63) == 0) { pa[wv] = a; pq[wv] = q; }
  __syncthreads();
  if (threadIdx.x == 0) {
    atomicAdd(&sum[c], pa[0] + pa[1] + pa[2] + pa[3]);
    atomicAdd(&sq[c], pq[0] + pq[1] + pq[2] + pq[3]);
  }
}

// Z master (hi/lo) += relu(bn(Z2 pair))
__global__ void ncl_updatez_pair(
    ushort* __restrict__ ZHi, ushort* __restrict__ ZLo,
    const ushort* __restrict__ Z2Hi, const ushort* __restrict__ Z2Lo,
    const float* __restrict__ g, const float* __restrict__ b,
    const float* __restrict__ sum, const float* __restrict__ sq)
{
  unsigned idx = blockIdx.x * 256u + threadIdx.x;
  if (idx >= (unsigned)NS * DE) return;
  unsigned s = idx / DE, rem = idx - s * DE;
  unsigned i = rem / RR, l = rem - i * RR;
  size_t off = (size_t)s * KH + i * 128 + l;
  const float invcnt = 1.f / (float)(NS * RR);
  float m = sum[i] * invcnt;
  float v = sq[i] * invcnt - m * m;
  float iv = rsqrtf(v + EPSF);
  float z2 = bf2f(Z2Hi[off]) + bf2f(Z2Lo[off]);
  float z = (z2 - m) * iv * g[i] + b[i];
  float nv = bf2f(ZHi[off]) + bf2f(ZLo[off]) + fmaxf(z, 0.f);
  ushort h = f2bf(nv);
  ZHi[off] = h;
  ZLo[off] = f2bf(nv - bf2f(h));
}

template<int LC>
__global__ __launch_bounds__(256) void ncl_stats(
    const float* __restrict__ Xv, float* __restrict__ sum, float* __restrict__ sq)
{
  const int c = blockIdx.x;
  const int s0 = blockIdx.y * 128;
  const int tot = 128 * LC;
  float a = 0.f, q = 0.f;
  for (int f = threadIdx.x; f < tot; f += 256) {
    int sl = f / LC, l = f - sl * LC;
    float v = Xv[((size_t)(s0 + sl) * RR + c) * LC + l];
    a += v; q += v * v;
  }
  for (int o = 32; o; o >>= 1) { a += __shfl_down(a, o); q += __shfl_down(q, o); }
  __shared__ float pa[4], pq[4];
  const int wv = threadIdx.x >> 6;
  if ((threadIdx.x & 63) == 0) { pa[wv] = a; pq[wv] = q; }
  __syncthreads();
  if (threadIdx.x == 0) {
    atomicAdd(&sum[c], pa[0] + pa[1] + pa[2] + pa[3]);
    atomicAdd(&sq[c], pq[0] + pq[1] + pq[2] + pq[3]);
  }
}

template<int LC>
__global__ void ncl_update(float* __restrict__ dst, const float* __restrict__ src,
                           const float* __restrict__ g, const float* __restrict__ b,
                           const float* __restrict__ sum, const float* __restrict__ sq,
                           float invcnt, unsigned total)
{
  unsigned idx = blockIdx.x * 256u + threadIdx.x;
  if (idx >= total) return;
  int c = (int)((idx / LC) % RR);
  float m = sum[c] * invcnt;
  float v = sq[c] * invcnt - m * m;
  float iv = rsqrtf(v + EPSF);
  float z = (src[idx] - m) * iv * g[c] + b[c];
  dst[idx] += fmaxf(z, 0.f);
}

__global__ void hpost(float* __restrict__ Hh, const float* __restrict__ b, unsigned total)
{
  unsigned idx = blockIdx.x * 256u + threadIdx.x;
  if (idx >= total) return;
  Hh[idx] = fmaxf(Hh[idx] + b[idx & (C1O - 1)], 0.f);
}

__global__ __launch_bounds__(256) void c2k(const float* __restrict__ Hh,
                                           const float* __restrict__ w,
                                           const float* __restrict__ b,
                                           float* __restrict__ out)
{
  const int s = blockIdx.x;
  float a0 = 0.f, a1 = 0.f;
  for (int j = threadIdx.x; j < C1O; j += 256) {
    float h = Hh[(size_t)s * C1O + j];
    a0 += h * w[j];
    a1 += h * w[C1O + j];
  }
  for (int o = 32; o; o >>= 1) { a0 += __shfl_down(a0, o); a1 += __shfl_down(a1, o); }
  __shared__ float p0[4], p1[4];
  const int wv = threadIdx.x >> 6;
  if ((threadIdx.x & 63) == 0) { p0[wv] = a0; p1[wv] = a1; }
  __syncthreads();
  if (threadIdx.x == 0) {
    out[s * 2 + 0] = p0[0] + p0[1] + p0[2] + p0[3] + b[0];
    out[s * 2 + 1] = p1[0] + p1[1] + p1[2] + p1[3] + b[1];
  }
}

// ---------------------------------------------------------------------------
extern "C" void kernel_launch(void* const* d_in, const int* in_sizes, int n_in,
                              void* d_out, int out_size, void* d_ws, size_t ws_size,
                              hipStream_t stream)
{
  const float* X    = (const float*)d_in[0];
  const float* Z    = (const float*)d_in[1];
  const float* cv1w = (const float*)d_in[2];
  const float* cv1b = (const float*)d_in[3];
  const float* cv2w = (const float*)d_in[4];
  const float* cv2b = (const float*)d_in[5];
  const float* nw   = (const float*)d_in[6];
  const float* ew   = (const float*)d_in[7];
  const float* bng  = (const float*)d_in[8];
  const float* bnb  = (const float*)d_in[9];
  const float* beg  = (const float*)d_in[10];
  const float* beb  = (const float*)d_in[11];
  const float* lnw  = (const float*)d_in[12];
  const float* lnb  = (const float*)d_in[13];
  const float* lng  = (const float*)d_in[14];
  const float* lnbt = (const float*)d_in[15];
  const float* lew  = (const float*)d_in[16];
  const float* leb  = (const float*)d_in[17];
  const float* leg  = (const float*)d_in[18];
  const float* lebt = (const float*)d_in[19];
  const float* fc1w = (const float*)d_in[20];
  const float* fc1b = (const float*)d_in[21];
  const float* fc2w = (const float*)d_in[22];
  const float* fc2b = (const float*)d_in[23];
  float* out = (float*)d_out;

  // workspace layout (~320 MiB total, well under proven 381.5 MB)
  char* base = (char*)d_ws;
  ushort* ZHi  = (ushort*)base;                     base += (size_t)NS * KH * 2;
  ushort* ZLo  = (ushort*)base;                     base += (size_t)NS * KH * 2;
  ushort* ARHi = (ushort*)base;                     base += (size_t)NS * KH * 2;
  ushort* ARLo = (ushort*)base;                     base += (size_t)NS * KH * 2;
  ushort* XZb  = (ushort*)base;                     base += (size_t)NS * XZC * 2;
  ushort* c1wh = (ushort*)base;                     base += (size_t)C1O * XZC * 2;
  ushort* lewh = (ushort*)base;                     base += (size_t)384 * KH * 2;
  ushort* w2Hi = (ushort*)base;                     base += (size_t)4 * KH * 2;
  ushort* w2Lo = (ushort*)base;                     base += (size_t)4 * KH * 2;
  ushort* eHi  = (ushort*)base;                     base += (size_t)4 * KH * 2;
  ushort* eLo  = (ushort*)base;                     base += (size_t)4 * KH * 2;
  float* Xb = (float*)base;                         base += (size_t)NS * DN * 4;
  float* X1 = (float*)base;                         base += (size_t)NS * DN * 4;
  float* XZ = (float*)base;                         base += (size_t)NS * XZC * 4;
  float* HH = (float*)base;                         base += (size_t)NS * C1O * 4;
  float* Kf = (float*)base;                         base += (size_t)NS * 384 * 4;
  float* ST = (float*)base;

  hipMemcpyAsync(Xb, X, sizeof(float) * (size_t)NS * DN, hipMemcpyDeviceToDevice, stream);
  hipMemsetAsync(XZ, 0, sizeof(float) * (size_t)NS * XZC, stream);
  hipMemsetAsync(HH, 0, sizeof(float) * (size_t)NS * C1O, stream);
  cvt_pad<<<(unsigned)(((long long)C1O * XZC + 255) / 256), 256, 0, stream>>>(
      fc1w, c1wh, (long long)C1O * XZC);
  wprep2<<<(4 * KH) / 256, 256, 0, stream>>>(cv2w, ew, w2Hi, w2Lo, eHi, eLo);
  cvtZ0<<<NS, 256, 0, stream>>>(Z, ZHi, ZLo);

  const float rinv = 1.f / (float)NS;

  auto head384 = [&](int hd, int cof) {
    lewprep<<<(384 * KH) / 256, 256, 0, stream>>>(lew + (size_t)hd * 384 * DE, lewh);
    gemm_mfma_tn<<<dim3(3, 16, 6), 256, 0, stream>>>(
        ZHi, KH, lewh, KH, XZ, XZC, cof, KH / 32);
    hipMemsetAsync(ST, 0, sizeof(float) * 768, stream);
    headpost<<<dim3(6, 8), 256, 0, stream>>>(XZ, XZC, cof, 384, 256,
                                             leb + hd * 384, ST, ST + 384);
    colnormb<384><<<(NS * 384 + 255) / 256, 256, 0, stream>>>(
        XZ, XZb, XZC, cof, rinv, ST, ST + 384, leg + hd * 384, lebt + hd * 384, NS * 384);
  };
  auto head128 = [&](int hd, int cof) {
    gemm64<<<dim3(2, NS / 64, 1), 256, 0, stream>>>(
        Xb, DN, lnw + (size_t)hd * HD * DN, DN, lnb + hd * HD, XZ, XZC, cof, NS, HD, DN);
    hipMemsetAsync(ST, 0, sizeof(float) * 768, stream);
    colstats<<<dim3(2, 8), 256, 0, stream>>>(XZ, XZC, cof, HD, 256, ST, ST + 384);
    colnormb<HD><<<(NS * HD + 255) / 256, 256, 0, stream>>>(
        XZ, XZb, XZC, cof, rinv, ST, ST + 384, lng + hd * HD, lnbt + hd * HD, NS * HD);
  };

  head128(0, 0);
  head384(0, 640);

  for (int i = 0; i < LLY; i++) {
    // K for this layer (old X)
    kprep<<<(NS * 384 + 255) / 256, 256, 0, stream>>>(Xb, cv1w + i * 9, cv1b + i * 3, Kf);
    // G1+G2 fused: A_ref pair <- softmax-chain (split-bf16, fp32-equivalent)
    fusedG12<<<NS, 256, 0, stream>>>(ZHi, ZLo, w2Hi + (size_t)i * KH, w2Lo + (size_t)i * KH,
                                     cv2b + i * RR, Kf, ARHi, ARLo);
    // node branch (old X)
    pTx_node<<<NS, 128, 0, stream>>>(ARHi, ARLo, Xb, nw + i * 9, X1);
    // G3+G4 fused: Z2 pair in place over A_ref pair (old Z)
    fusedG34<<<NS, 256, 0, stream>>>(ZHi, ZLo, eHi + (size_t)i * KH, eLo + (size_t)i * KH,
                                     ARHi, ARLo);
    // BN + residual
    hipMemsetAsync(ST + 768, 0, sizeof(float) * 512, stream);
    ncl_statsb_pair<<<dim3(RR, 16), 256, 0, stream>>>(ARHi, ARLo, ST + 768, ST + 768 + 128);
    ncl_stats<3><<<dim3(RR, 16), 256, 0, stream>>>(X1, ST + 768 + 256, ST + 768 + 384);
    ncl_updatez_pair<<<((unsigned)NS * DE + 255) / 256, 256, 0, stream>>>(
        ZHi, ZLo, ARHi, ARLo, beg + i * RR, beb + i * RR, ST + 768, ST + 768 + 128);
    ncl_update<3><<<((unsigned)NS * DN + 255) / 256, 256, 0, stream>>>(
        Xb, X1, bng + i * RR, bnb + i * RR, ST + 768 + 256, ST + 768 + 384,
        1.f / (float)(NS * 3), (unsigned)NS * DN);
    // heads on updated Z and X
    head384(i + 1, 640 + (i + 1) * 384);
    head128(i + 1, (i + 1) * HD);
  }

  // c1: h = relu(XZb @ c1_w^T + b) via bf16 MFMA split-K=2
  gemm_mfma_tn<<<dim3(C1O / 128, NS / 128, 2), 256, 0, stream>>>(
      XZb, XZC, c1wh, XZC, HH, C1O, 0, XZC / 32);
  hpost<<<((unsigned)NS * C1O + 255) / 256, 256, 0, stream>>>(HH, fc1b, (unsigned)NS * C1O);
  c2k<<<NS, 256, 0, stream>>>(HH, fc2w, fc2b, out);
}